// Round 7
// baseline (178.966 us; speedup 1.0000x reference)
//
#include <hip/hip_runtime.h>
#include <float.h>

// Problem constants (from reference setup_inputs)
#define B_SZ 2
#define N_SZ 16384                  // N == M
#define E_SZ 49152

#define TPB 512
#define WAVES (TPB / 64)            // 8
#define ROWS_PER_BLOCK 128          // 2 row-pairs x 64 rows; 4 col-groups
#define NTILES (N_SZ / 32)          // 512 col-tiles per batch
#define TILES_PER_CG (NTILES / 4)   // 128 tiles per col-group

// ONE pass per matrix entry: 256 chamfer blocks (2 batch x 128 row-blocks).
// Row-mins (pred->tgt) in registers; col-mins (tgt->pred) from the SAME
// MFMA results via per-tile tree + LDS atomicMin + global atomicMin.
#define CH_BLOCKS (B_SZ * N_SZ / ROWS_PER_BLOCK)          // 256
#define EDGE_BLOCKS (B_SZ * E_SZ / TPB)                   // 192

// frag workspace: per batch: plane0 [16384 x 16B] then plane1 (tgt only now)
#define PLANE_BYTES (N_SZ * 16)                 // 256 KB
#define BATCH_FRAG_BYTES (2 * PLANE_BYTES)      // 512 KB
#define DIR_FRAG_BYTES (B_SZ * BATCH_FRAG_BYTES) // 1 MB
// col-min global array lives in the (now unused) dir-1 frag region:
#define COLMIN_OFF DIR_FRAG_BYTES               // 2 x 16384 ints = 128 KB
#define SUMS_OFF (2 * DIR_FRAG_BYTES)           // 2 MB (ws footprint unchanged)

typedef short short8 __attribute__((ext_vector_type(8)));
typedef float f32x16 __attribute__((ext_vector_type(16)));

// ---- bf16 bit helpers (RNE); inputs are finite Gaussians ----
__device__ inline short f2bf(float f) {
    unsigned u = __float_as_uint(f);
    unsigned r = (u + 0x7fffu + ((u >> 16) & 1u)) >> 16;
    return (short)r;
}
__device__ inline float bf2f(short s) {
    return __uint_as_float(((unsigned)(unsigned short)s) << 16);
}

// ---- prep: convert tgt points to B-operand fragments + init colmin/sums ----
// B-rep per point t: plane0 {thx,thy,thz,thx,thy,thz,1,1}
//                    plane1 {tlx,tly,tlz,t2h,t2l,0,0,0}
__global__ __launch_bounds__(TPB) void prep(const float* __restrict__ tgt,
                                            char* __restrict__ ws) {
    int idx = blockIdx.x * TPB + threadIdx.x;       // 0..32767
    double* sums = (double*)(ws + SUMS_OFF);
    if (blockIdx.x == 0 && threadIdx.x < 6) sums[threadIdx.x] = 0.0;
    ((int*)(ws + COLMIN_OFF))[idx] = 0x7f7fffff;    // colmin init (FLT_MAX bits)

    int batch = idx >> 14, pt = idx & (N_SZ - 1);
    const float* src = tgt + (size_t)idx * 3;
    char* base = ws + (size_t)batch * BATCH_FRAG_BYTES;

    float tx = src[0], ty = src[1], tz = src[2];
    short hx = f2bf(tx), hy = f2bf(ty), hz = f2bf(tz);
    short lx = f2bf(tx - bf2f(hx)), ly = f2bf(ty - bf2f(hy)), lz = f2bf(tz - bf2f(hz));
    float t2 = fmaf(tx, tx, fmaf(ty, ty, tz * tz));
    short t2h = f2bf(t2), t2l = f2bf(t2 - bf2f(t2h));
    const short one = 0x3f80;

    *(short8*)(base + (size_t)pt * 16) = (short8){hx, hy, hz, hx, hy, hz, one, one};
    *(short8*)(base + PLANE_BYTES + (size_t)pt * 16) =
        (short8){lx, ly, lz, t2h, t2l, 0, 0, 0};
}

// ---- main: ONE-PASS chamfer (row-min AND col-min of the same tiles) + edge --
// d^2 = (-2p).t + p^2 + t^2 via K=13 bf16 hi/lo split in ONE 32x32x16 MFMA.
// A lane: m=lane&31, k=(lane>>5)*8+j:
//   half0 (k0-7):  {ahx,ahy,ahz, alx,aly,alz, p2h,p2l}   (a = -2p)
//   half1 (k8-15): {ahx,ahy,ahz, 1, 1, 0,0,0}
// C/D (verified m74/m101): col=lane&31, row=(reg&3)+8*(reg>>2)+4*(lane>>5).
//
// R13 rationale: R6/R8/R11/R12 (four structures: LDS-chunk, dbuf+2xocc,
// asm-min3, no-LDS streaming) ALL land 46-52us with MfmaUtil~27 VALU~41 --
// scheduling-level fixes are exhausted; the robust lever is 2x LESS WORK.
// The two chamfer directions share one distance matrix: row-mins as before,
// col-mins from the SAME results: per-lane the 16 C-regs are 16 rows of one
// column -> register tree (r,s = both row-tiles) + shfl_xor(32) + per-wave
// LDS atomicMin (1 per col per tile) + per-block global atomicMin (guarded).
//  - (512,2) budget, 1-iter-ahead 4-tile register prefetch (R12 base).
//  - fminf chains only (R5/R6 hazard lesson; R11 proved min3-asm neutral).
__global__ __launch_bounds__(TPB, 2) void main_kernel(
    const float* __restrict__ pred, const float* __restrict__ tgt,
    const int* __restrict__ edges, char* __restrict__ ws)
{
    __shared__ int colLds[N_SZ];            // 64 KB: block-level col-mins
    __shared__ float wred[WAVES], wred2[WAVES];
    __shared__ int rowMin[ROWS_PER_BLOCK];
    double* sums = (double*)(ws + SUMS_OFF);
    const int lane = threadIdx.x & 63;
    const int wv = threadIdx.x >> 6;
    const int t = threadIdx.x;

    if (blockIdx.x < CH_BLOCKS) {
        const int batch = blockIdx.x >> 7;
        const int rowInB = (blockIdx.x & 127) * ROWS_PER_BLOCK;
        const char* fragBase = ws + (size_t)batch * BATCH_FRAG_BYTES;
        const int bl = lane & 31;
        const int half = lane >> 5;
        const int rp = wv & 1;                    // row-pair: which 64 rows
        const int cg = wv >> 1;                   // col-group: 128 tiles each

        for (int k = t; k < N_SZ; k += TPB) colLds[k] = 0x7f7fffff;
        if (t < ROWS_PER_BLOCK) rowMin[t] = 0x7f7fffff;

        // ---- A fragments for the wave's two row tiles (rows from pred) ----
        const short one = 0x3f80;
        short8 af[2];
        #pragma unroll
        for (int j = 0; j < 2; j++) {
            int r = batch * N_SZ + rowInB + rp * 64 + j * 32 + bl;
            const float* p = pred + (size_t)r * 3;
            float px = p[0], py = p[1], pz = p[2];
            float ax = -2.f * px, ay = -2.f * py, az = -2.f * pz;
            short ahx = f2bf(ax), ahy = f2bf(ay), ahz = f2bf(az);
            short alx = f2bf(ax - bf2f(ahx)), aly = f2bf(ay - bf2f(ahy)),
                  alz = f2bf(az - bf2f(ahz));
            float p2 = fmaf(px, px, fmaf(py, py, pz * pz));
            short p2h = f2bf(p2), p2l = f2bf(p2 - bf2f(p2h));
            af[j] = half == 0
                ? (short8){ahx, ahy, ahz, alx, aly, alz, p2h, p2l}
                : (short8){ahx, ahy, ahz, one, one, 0, 0, 0};
        }

        float acc0[16], acc1[16];
        #pragma unroll
        for (int e = 0; e < 16; e++) { acc0[e] = FLT_MAX; acc1[e] = FLT_MAX; }
        const f32x16 zc = {0.f, 0.f, 0.f, 0.f, 0.f, 0.f, 0.f, 0.f,
                           0.f, 0.f, 0.f, 0.f, 0.f, 0.f, 0.f, 0.f};

        // ---- B stream: this wave's 128 tiles, straight from global (L2) ----
        const char* bbase = fragBase + (size_t)half * PLANE_BYTES
                                     + (size_t)bl * 16;
        const int tbase = cg * TILES_PER_CG;
        auto ldb = [&](int tc) {
            return *(const short8*)(bbase + (size_t)tc * 512);
        };
        // col-min tree for one tile: r,s = results of both row-tiles (32 rows
        // in this lane+its 16 regs x2); then xor-32 combines the other half.
        auto coltree = [&](const f32x16& r, const f32x16& s, int tc) {
            float m[8];
            #pragma unroll
            for (int e = 0; e < 8; e++)
                m[e] = fminf(fminf(r[e], r[e + 8]), fminf(s[e], s[e + 8]));
            float cv = fminf(fminf(fminf(m[0], m[1]), fminf(m[2], m[3])),
                             fminf(fminf(m[4], m[5]), fminf(m[6], m[7])));
            cv = fminf(cv, __shfl_xor(cv, 32));
            if (half == 0)
                atomicMin(&colLds[tc * 32 + bl], __float_as_int(fmaxf(cv, 0.f)));
        };
        // 2 col-tiles x 2 row-tiles = 4 MFMAs; row-min pairs + 2 col trees.
        auto dopair = [&](short8 x0, short8 x1, int tc0) {
            f32x16 r0 = __builtin_amdgcn_mfma_f32_32x32x16_bf16(af[0], x0, zc, 0, 0, 0);
            f32x16 r1 = __builtin_amdgcn_mfma_f32_32x32x16_bf16(af[0], x1, zc, 0, 0, 0);
            f32x16 s0 = __builtin_amdgcn_mfma_f32_32x32x16_bf16(af[1], x0, zc, 0, 0, 0);
            f32x16 s1 = __builtin_amdgcn_mfma_f32_32x32x16_bf16(af[1], x1, zc, 0, 0, 0);
            #pragma unroll
            for (int e = 0; e < 16; e++)
                acc0[e] = fminf(fminf(r0[e], r1[e]), acc0[e]);
            #pragma unroll
            for (int e = 0; e < 16; e++)
                acc1[e] = fminf(fminf(s0[e], s1[e]), acc1[e]);
            coltree(r0, s0, tc0);
            coltree(r1, s1, tc0 + 1);
        };

        short8 b0 = ldb(tbase + 0), b1 = ldb(tbase + 1);
        short8 b2 = ldb(tbase + 2), b3 = ldb(tbase + 3);
        __syncthreads();                          // colLds/rowMin init visible

        #pragma unroll 1
        for (int i = 0; i < TILES_PER_CG / 4; i++) {   // 32 iters x 4 tiles
            int tc = tbase + 4 * i;
            int pf = (i < TILES_PER_CG / 4 - 1) ? tc + 4 : tbase;
            {
                short8 x0 = b0, x1 = b1;
                b0 = ldb(pf + 0); b1 = ldb(pf + 1);    // prefetch, 1 iter ahead
                dopair(x0, x1, tc);
            }
            {
                short8 x0 = b2, x1 = b3;
                b2 = ldb(pf + 2); b3 = ldb(pf + 3);
                dopair(x0, x1, tc + 2);
            }
        }

        // ---- row path: fold 32 col-lanes, per-row minima via LDS atomicMin --
        #pragma unroll
        for (int j = 0; j < 2; j++) {
            #pragma unroll
            for (int e = 0; e < 16; e++) {
                float v = (j == 0) ? acc0[e] : acc1[e];
                v = fminf(v, __shfl_xor(v, 1));
                v = fminf(v, __shfl_xor(v, 2));
                v = fminf(v, __shfl_xor(v, 4));
                v = fminf(v, __shfl_xor(v, 8));
                v = fminf(v, __shfl_xor(v, 16));
                if (bl == 0) {
                    int row = rp * 64 + j * 32 + (e & 3) + 8 * (e >> 2) + 4 * half;
                    atomicMin(&rowMin[row], __float_as_int(fmaxf(v, 0.f)));
                }
            }
        }
        __syncthreads();

        // ---- row sums ----
        if (t < ROWS_PER_BLOCK) {
            float s = sqrtf(__int_as_float(rowMin[t]));
            #pragma unroll
            for (int o = 32; o > 0; o >>= 1) s += __shfl_down(s, o, 64);
            if (lane == 0) wred[wv] = s;
        }
        __syncthreads();
        if (t == 0) atomicAdd(&sums[0], (double)(wred[0] + wred[1]));

        // ---- col publish: block partials -> global colmin (guarded atomic) --
        int* colG = (int*)(ws + COLMIN_OFF) + batch * N_SZ;
        for (int k = t; k < N_SZ; k += TPB) {
            int v = colLds[k];
            if (v < colG[k]) atomicMin(&colG[k], v);
        }
    } else {
        // ---- edge loss (int32 edges per harness convention) ----
        int idx = (blockIdx.x - CH_BLOCKS) * TPB + threadIdx.x;  // 0..98303
        int b = idx >= E_SZ;                        // block-uniform (96 blocks/b)
        int e = idx - b * E_SZ;
        int2 ee = ((const int2*)edges)[e];
        const float* p0 = pred + ((size_t)b * N_SZ + (size_t)ee.x) * 3;
        const float* p1 = pred + ((size_t)b * N_SZ + (size_t)ee.y) * 3;
        float dx = p0[0] - p1[0], dy = p0[1] - p1[1], dz = p0[2] - p1[2];
        float len = sqrtf(dx * dx + dy * dy + dz * dz);
        float s = len, q = len * len;
        for (int o = 32; o > 0; o >>= 1) {
            s += __shfl_down(s, o, 64);
            q += __shfl_down(q, o, 64);
        }
        if (lane == 0) { wred[wv] = s; wred2[wv] = q; }
        __syncthreads();
        if (threadIdx.x == 0) {
            float ts = 0.f, tq = 0.f;
            #pragma unroll
            for (int w = 0; w < WAVES; w++) { ts += wred[w]; tq += wred2[w]; }
            atomicAdd(&sums[2 + 2 * b], (double)ts);
            atomicAdd(&sums[3 + 2 * b], (double)tq);
        }
    }
}

// ---- colsum: sqrt + sum the global col-mins into sums[1] ----
__global__ __launch_bounds__(TPB) void colsum_kernel(char* __restrict__ ws) {
    __shared__ float wr[WAVES];
    const int* colG = (const int*)(ws + COLMIN_OFF);
    double* sums = (double*)(ws + SUMS_OFF);
    int idx = blockIdx.x * TPB + threadIdx.x;       // 0..32767 (grid 64)
    float v = sqrtf(__int_as_float(colG[idx]));
    #pragma unroll
    for (int o = 32; o > 0; o >>= 1) v += __shfl_down(v, o, 64);
    if ((threadIdx.x & 63) == 0) wr[threadIdx.x >> 6] = v;
    __syncthreads();
    if (threadIdx.x == 0) {
        float s = 0.f;
        #pragma unroll
        for (int w = 0; w < WAVES; w++) s += wr[w];
        atomicAdd(&sums[1], (double)s);
    }
}

// ---- combine to the 3 outputs ----
__global__ void final_kernel(const char* __restrict__ ws, float* __restrict__ out) {
    const double* sums = (const double*)(ws + SUMS_OFF);
    double c = sums[0] / (double)(B_SZ * N_SZ) + sums[1] / (double)(B_SZ * N_SZ);
    double e = 0.0;
    #pragma unroll
    for (int b = 0; b < B_SZ; b++) {
        double s = sums[2 + 2 * b], q = sums[3 + 2 * b];
        e += (q - s * s / (double)E_SZ) / (double)(E_SZ - 1);
    }
    e *= (1.0 / B_SZ);
    double tot = 1.0 * c + 0.1 * e;
    out[0] = (float)tot;
    out[1] = (float)c;
    out[2] = (float)e;
}

extern "C" void kernel_launch(void* const* d_in, const int* in_sizes, int n_in,
                              void* d_out, int out_size, void* d_ws, size_t ws_size,
                              hipStream_t stream) {
    const float* pred = (const float*)d_in[0];       // (B, N, 3) fp32
    const float* tgt  = (const float*)d_in[1];       // (B, M, 3) fp32
    const int* edges  = (const int*)d_in[2];         // (E, 2) int32 (harness-converted)
    float* out = (float*)d_out;
    char* ws = (char*)d_ws;                          // needs 2 MB + 48 B

    // 1) tgt -> MFMA B-fragments; init colmin + sums
    prep<<<dim3((B_SZ * N_SZ) / TPB), TPB, 0, stream>>>(tgt, ws);

    // 2) one-pass chamfer (256 blocks: row-min AND col-min) + edge (192 blocks)
    main_kernel<<<dim3(CH_BLOCKS + EDGE_BLOCKS), TPB, 0, stream>>>(
        pred, tgt, edges, ws);

    // 3) reduce global col-mins
    colsum_kernel<<<dim3((B_SZ * N_SZ) / TPB), TPB, 0, stream>>>(ws);

    // 4) combine
    final_kernel<<<dim3(1), dim3(1), 0, stream>>>(ws, out);
}

// Round 8
// 113.524 us; speedup vs baseline: 1.5765x; 1.5765x over previous
//
#include <hip/hip_runtime.h>
#include <float.h>

// Problem constants (from reference setup_inputs)
#define B_SZ 2
#define N_SZ 16384                  // N == M
#define E_SZ 49152

#define TPB 512
#define WAVES (TPB / 64)            // 8
#define ROWS_PER_BLOCK 128          // 2 row-pairs x 64 rows; 4 col-groups
#define NTILES (N_SZ / 32)          // 512 col-tiles per (dir,batch)
#define TILES_PER_CG (NTILES / 4)   // 128 tiles per col-group

#define CH_BLOCKS_PER_DIR (B_SZ * N_SZ / ROWS_PER_BLOCK)  // 256
#define CH_BLOCKS (2 * CH_BLOCKS_PER_DIR)                 // 512
#define EDGE_BLOCKS (B_SZ * E_SZ / TPB)                   // 192

// frag workspace: per dir, per batch: plane0 [16384 x 16B] then plane1
#define PLANE_BYTES (N_SZ * 16)                 // 256 KB
#define BATCH_FRAG_BYTES (2 * PLANE_BYTES)      // 512 KB
#define DIR_FRAG_BYTES (B_SZ * BATCH_FRAG_BYTES) // 1 MB
#define SUMS_OFF (2 * DIR_FRAG_BYTES)           // 2 MB

typedef short short8 __attribute__((ext_vector_type(8)));
typedef float f32x16 __attribute__((ext_vector_type(16)));

// ---- bf16 bit helpers (RNE); inputs are finite Gaussians ----
__device__ inline short f2bf(float f) {
    unsigned u = __float_as_uint(f);
    unsigned r = (u + 0x7fffu + ((u >> 16) & 1u)) >> 16;
    return (short)r;
}
__device__ inline float bf2f(short s) {
    return __uint_as_float(((unsigned)(unsigned short)s) << 16);
}

// ---- prep: convert every point to B-operand fragments + zero sums ----
// B-rep per point t (search-set role):
//   plane0 (k0-7):  {thx,thy,thz, thx,thy,thz, 1, 1}
//   plane1 (k8-15): {tlx,tly,tlz, t2h,t2l, 0,0,0}
// idx 0..32767: tgt points -> dir0 buffer; 32768..65535: pred -> dir1 buffer.
__global__ __launch_bounds__(TPB) void prep(const float* __restrict__ pred,
                                            const float* __restrict__ tgt,
                                            char* __restrict__ ws) {
    int idx = blockIdx.x * TPB + threadIdx.x;       // 0..65535
    double* sums = (double*)(ws + SUMS_OFF);
    if (blockIdx.x == 0 && threadIdx.x < 6) sums[threadIdx.x] = 0.0;

    const bool isTgt = idx < B_SZ * N_SZ;
    int row = isTgt ? idx : idx - B_SZ * N_SZ;      // 0..32767
    int batch = row >> 14, pt = row & (N_SZ - 1);
    const float* src = (isTgt ? tgt : pred) + (size_t)row * 3;
    char* base = ws + (isTgt ? 0 : DIR_FRAG_BYTES) + (size_t)batch * BATCH_FRAG_BYTES;

    float tx = src[0], ty = src[1], tz = src[2];
    short hx = f2bf(tx), hy = f2bf(ty), hz = f2bf(tz);
    short lx = f2bf(tx - bf2f(hx)), ly = f2bf(ty - bf2f(hy)), lz = f2bf(tz - bf2f(hz));
    float t2 = fmaf(tx, tx, fmaf(ty, ty, tz * tz));
    short t2h = f2bf(t2), t2l = f2bf(t2 - bf2f(t2h));
    const short one = 0x3f80;

    *(short8*)(base + (size_t)pt * 16) = (short8){hx, hy, hz, hx, hy, hz, one, one};
    *(short8*)(base + PLANE_BYTES + (size_t)pt * 16) =
        (short8){lx, ly, lz, t2h, t2l, 0, 0, 0};
}

// ---- main: chamfer (both directions) + edge ----
// d^2 = (-2p).t + p^2 + t^2 via K=13 bf16 hi/lo split in ONE 32x32x16 MFMA.
// A lane: m=lane&31, k=(lane>>5)*8+j:
//   half0 (k0-7):  {ahx,ahy,ahz, alx,aly,alz, p2h,p2l}   (a = -2p)
//   half1 (k8-15): {ahx,ahy,ahz, 1, 1, 0,0,0}
// C/D (verified m74/m101): col=lane&31, row=(reg&3)+8*(reg>>2)+4*(lane>>5).
//
// R14 = R12 streaming base + SOFTWARE PIPELINE, the two untested levers:
// R6/R8/R11/R12 all show ~30% no-issue cycles (Mfma 27 + VALU 41); occupancy,
// min-flavor, LDS/barriers are proven nulls. What never varied: (a) every
// version reduced MFMA results IMMEDIATELY after issue (full MFMA latency on
// the wave's critical path per pair); (b) prefetch depth 1 (~4 tiles) vs
// 200-400cyc L2 latency. Fix both:
//  - result pipeline: STEP issues pair k's 4 MFMAs, then reduces pair k-1's
//    results (~90 cyc of independent work before first consumer).
//  - 8-tile register ring, reload-on-consume: distance 4 STEPs (~440 cyc).
//  - all rotation via STATIC names (A/B sets, b0..b7), 4 STEPs per unroll-1
//    iter (R9/rule-20: runtime-indexed regs -> scratch).
//  - reg math: results 128 + acc 32 + ring 32 + af 8 + addr ~ 210 < 256 of
//    (512,2). WRITE_SIZE ~28KB is the spill sentinel.
//  - fminf chains only (R5/R6 hazard; R11: min3-asm neutral).
__global__ __launch_bounds__(TPB, 2) void main_kernel(
    const float* __restrict__ pred, const float* __restrict__ tgt,
    const int* __restrict__ edges, char* __restrict__ ws)
{
    __shared__ float wred[WAVES], wred2[WAVES];
    __shared__ int rowMin[ROWS_PER_BLOCK];
    double* sums = (double*)(ws + SUMS_OFF);
    const int lane = threadIdx.x & 63;
    const int wv = threadIdx.x >> 6;
    const int t = threadIdx.x;

    if (blockIdx.x < CH_BLOCKS) {
        const int dir = blockIdx.x >> 8;          // 0: rows=pred, search tgt
        const int xb = blockIdx.x & 255;
        const int batch = xb >> 7;
        const int rowInB = (xb & 127) * ROWS_PER_BLOCK;
        const float* P = dir ? tgt : pred;
        const char* fragBase = ws + (size_t)dir * DIR_FRAG_BYTES
                                  + (size_t)batch * BATCH_FRAG_BYTES;
        const int bl = lane & 31;
        const int half = lane >> 5;
        const int rp = wv & 1;                    // row-pair: which 64 rows
        const int cg = wv >> 1;                   // col-group: 128 tiles each

        if (t < ROWS_PER_BLOCK) rowMin[t] = 0x7f7fffff;   // FLT_MAX bits

        // ---- A fragments for the wave's two row tiles ----
        const short one = 0x3f80;
        short8 af[2];
        #pragma unroll
        for (int j = 0; j < 2; j++) {
            int r = batch * N_SZ + rowInB + rp * 64 + j * 32 + bl;
            const float* p = P + (size_t)r * 3;
            float px = p[0], py = p[1], pz = p[2];
            float ax = -2.f * px, ay = -2.f * py, az = -2.f * pz;
            short ahx = f2bf(ax), ahy = f2bf(ay), ahz = f2bf(az);
            short alx = f2bf(ax - bf2f(ahx)), aly = f2bf(ay - bf2f(ahy)),
                  alz = f2bf(az - bf2f(ahz));
            float p2 = fmaf(px, px, fmaf(py, py, pz * pz));
            short p2h = f2bf(p2), p2l = f2bf(p2 - bf2f(p2h));
            af[j] = half == 0
                ? (short8){ahx, ahy, ahz, alx, aly, alz, p2h, p2l}
                : (short8){ahx, ahy, ahz, one, one, 0, 0, 0};
        }

        float acc0[16], acc1[16];
        #pragma unroll
        for (int e = 0; e < 16; e++) { acc0[e] = FLT_MAX; acc1[e] = FLT_MAX; }
        const f32x16 zc = {0.f, 0.f, 0.f, 0.f, 0.f, 0.f, 0.f, 0.f,
                           0.f, 0.f, 0.f, 0.f, 0.f, 0.f, 0.f, 0.f};
        const f32x16 fm = {FLT_MAX, FLT_MAX, FLT_MAX, FLT_MAX,
                           FLT_MAX, FLT_MAX, FLT_MAX, FLT_MAX,
                           FLT_MAX, FLT_MAX, FLT_MAX, FLT_MAX,
                           FLT_MAX, FLT_MAX, FLT_MAX, FLT_MAX};

        // ---- B stream: 128 tiles straight from global (L2-resident) ----
        // lane's 16B for tile tc: fragBase + half*PLANE + (tc*32 + bl)*16
        const char* bbase = fragBase + (size_t)half * PLANE_BYTES
                                     + (size_t)bl * 16;
        const char* bp = bbase + (size_t)(cg * TILES_PER_CG) * 512;

        // ring prologue: tiles 0..7 of this wave's col-group
        short8 b0 = *(const short8*)(bp + 0 * 512);
        short8 b1 = *(const short8*)(bp + 1 * 512);
        short8 b2 = *(const short8*)(bp + 2 * 512);
        short8 b3 = *(const short8*)(bp + 3 * 512);
        short8 b4 = *(const short8*)(bp + 4 * 512);
        short8 b5 = *(const short8*)(bp + 5 * 512);
        short8 b6 = *(const short8*)(bp + 6 * 512);
        short8 b7 = *(const short8*)(bp + 7 * 512);

        // result sets: A and B alternate as {issue-target / reduce-source}
        f32x16 Ap0, Ap1, Aq0, Aq1;
        f32x16 Bp0 = fm, Bp1 = fm, Bq0 = fm, Bq1 = fm;   // dummy first reduce

        // STEP: issue 4 MFMAs on (BX0,BX1) into CUR, reload the two ring
        // slots from 8 tiles ahead, reduce PRV (issued one STEP earlier).
        #define STEP(BX0, BX1, CUR, PRV, PF)                                   \
            do {                                                               \
                CUR##p0 = __builtin_amdgcn_mfma_f32_32x32x16_bf16(af[0], BX0, zc, 0, 0, 0); \
                CUR##p1 = __builtin_amdgcn_mfma_f32_32x32x16_bf16(af[0], BX1, zc, 0, 0, 0); \
                CUR##q0 = __builtin_amdgcn_mfma_f32_32x32x16_bf16(af[1], BX0, zc, 0, 0, 0); \
                CUR##q1 = __builtin_amdgcn_mfma_f32_32x32x16_bf16(af[1], BX1, zc, 0, 0, 0); \
                BX0 = *(const short8*)(bp + (PF) * 512);                       \
                BX1 = *(const short8*)(bp + ((PF) + 1) * 512);                 \
                _Pragma("unroll")                                              \
                for (int e = 0; e < 16; e++)                                   \
                    acc0[e] = fminf(fminf(PRV##p0[e], PRV##p1[e]), acc0[e]);   \
                _Pragma("unroll")                                              \
                for (int e = 0; e < 16; e++)                                   \
                    acc1[e] = fminf(fminf(PRV##q0[e], PRV##q1[e]), acc1[e]);   \
            } while (0)

        __syncthreads();                          // rowMin init visible

        #pragma unroll 1
        for (int i = 0; i < TILES_PER_CG / 8; i++) {   // 16 iters x 8 tiles
            STEP(b0, b1, A, B, 8);
            STEP(b2, b3, B, A, 10);
            STEP(b4, b5, A, B, 12);
            STEP(b6, b7, B, A, 14);
            bp += 8 * 512;
        }
        // epilogue: last issued set is B (STEP4 of final iter)
        #pragma unroll
        for (int e = 0; e < 16; e++)
            acc0[e] = fminf(fminf(Bp0[e], Bp1[e]), acc0[e]);
        #pragma unroll
        for (int e = 0; e < 16; e++)
            acc1[e] = fminf(fminf(Bq0[e], Bq1[e]), acc1[e]);
        #undef STEP

        // ---- fold 32 col-lanes, publish per-row minima via LDS atomicMin ----
        #pragma unroll
        for (int j = 0; j < 2; j++) {
            #pragma unroll
            for (int e = 0; e < 16; e++) {
                float v = (j == 0) ? acc0[e] : acc1[e];
                v = fminf(v, __shfl_xor(v, 1));
                v = fminf(v, __shfl_xor(v, 2));
                v = fminf(v, __shfl_xor(v, 4));
                v = fminf(v, __shfl_xor(v, 8));
                v = fminf(v, __shfl_xor(v, 16));
                if (bl == 0) {
                    int row = rp * 64 + j * 32 + (e & 3) + 8 * (e >> 2) + 4 * half;
                    atomicMin(&rowMin[row], __float_as_int(fmaxf(v, 0.f)));
                }
            }
        }
        __syncthreads();

        // ---- sqrt + block sum (rows live in threads 0..127 = waves 0,1) ----
        if (t < ROWS_PER_BLOCK) {
            float s = sqrtf(__int_as_float(rowMin[t]));
            #pragma unroll
            for (int o = 32; o > 0; o >>= 1) s += __shfl_down(s, o, 64);
            if (lane == 0) wred[wv] = s;
        }
        __syncthreads();
        if (t == 0) atomicAdd(&sums[dir], (double)(wred[0] + wred[1]));
    } else {
        // ---- edge loss (int32 edges per harness convention) ----
        int idx = (blockIdx.x - CH_BLOCKS) * TPB + threadIdx.x;  // 0..98303
        int b = idx >= E_SZ;                        // block-uniform (96 blocks/b)
        int e = idx - b * E_SZ;
        int2 ee = ((const int2*)edges)[e];
        const float* p0 = pred + ((size_t)b * N_SZ + (size_t)ee.x) * 3;
        const float* p1 = pred + ((size_t)b * N_SZ + (size_t)ee.y) * 3;
        float dx = p0[0] - p1[0], dy = p0[1] - p1[1], dz = p0[2] - p1[2];
        float len = sqrtf(dx * dx + dy * dy + dz * dz);
        float s = len, q = len * len;
        for (int o = 32; o > 0; o >>= 1) {
            s += __shfl_down(s, o, 64);
            q += __shfl_down(q, o, 64);
        }
        if (lane == 0) { wred[wv] = s; wred2[wv] = q; }
        __syncthreads();
        if (threadIdx.x == 0) {
            float ts = 0.f, tq = 0.f;
            #pragma unroll
            for (int w = 0; w < WAVES; w++) { ts += wred[w]; tq += wred2[w]; }
            atomicAdd(&sums[2 + 2 * b], (double)ts);
            atomicAdd(&sums[3 + 2 * b], (double)tq);
        }
    }
}

// ---- combine to the 3 outputs ----
__global__ void final_kernel(const char* __restrict__ ws, float* __restrict__ out) {
    const double* sums = (const double*)(ws + SUMS_OFF);
    double c = sums[0] / (double)(B_SZ * N_SZ) + sums[1] / (double)(B_SZ * N_SZ);
    double e = 0.0;
    #pragma unroll
    for (int b = 0; b < B_SZ; b++) {
        double s = sums[2 + 2 * b], q = sums[3 + 2 * b];
        e += (q - s * s / (double)E_SZ) / (double)(E_SZ - 1);
    }
    e *= (1.0 / B_SZ);
    double tot = 1.0 * c + 0.1 * e;
    out[0] = (float)tot;
    out[1] = (float)c;
    out[2] = (float)e;
}

extern "C" void kernel_launch(void* const* d_in, const int* in_sizes, int n_in,
                              void* d_out, int out_size, void* d_ws, size_t ws_size,
                              hipStream_t stream) {
    const float* pred = (const float*)d_in[0];       // (B, N, 3) fp32
    const float* tgt  = (const float*)d_in[1];       // (B, M, 3) fp32
    const int* edges  = (const int*)d_in[2];         // (E, 2) int32 (harness-converted)
    float* out = (float*)d_out;
    char* ws = (char*)d_ws;                          // needs 2 MB + 48 B

    // 1) convert points to MFMA B-fragments + zero sums
    prep<<<dim3((2 * B_SZ * N_SZ) / TPB), TPB, 0, stream>>>(pred, tgt, ws);

    // 2) chamfer (512 blocks, both dirs, complete row-mins) + edge (192 blocks)
    main_kernel<<<dim3(CH_BLOCKS + EDGE_BLOCKS), TPB, 0, stream>>>(
        pred, tgt, edges, ws);

    // 3) combine
    final_kernel<<<dim3(1), dim3(1), 0, stream>>>(ws, out);
}